// Round 6
// baseline (482.961 us; speedup 1.0000x reference)
//
#include <hip/hip_runtime.h>
#include <hip/hip_bf16.h>

// LocalPushLoss on MI355X (gfx950).
// losses[i] = max(0, M_i - thr_i),
//   M_i  = max over j with target[j]!=target[i] of <emb_i, emb_j>
//   thr_i = max(cos_theta[i, target[i]], 0.1) - 0.1
// out = mean(losses). bf16 MFMA GEMM E*E^T (N=16384, D=256) + fused masked
// row-max. 137.4 GFLOP -> 54.6us floor.
//
// Round-4 changes (from counters: WRITE_SIZE=15.9MB = scratch spills,
// VGPR_Count=128 cap, MfmaUtil 18%):
//  - WR 64->32: per-wave demand ~155 regs, __launch_bounds__(256,3) ->
//    no spill, 3 waves/SIMD.
//  - grid 512 -> 1024 blocks (BM=128): more TLP.
//  - prep rewritten: LDS-staged tile transpose -> fully coalesced writes
//    (old version scattered 8-B granules).
// embT layout (verified absmax=0.0 in round 3):
//   byte(tile,ch,kk,khc,half) = tile*32768 + ch*16384 + kk*1024
//                             + (kh*32+c)*16 + half*8
//   row = tile*64 + ch*32 + c ; elements k = kk*16 + kh*8 + half*4 ..+4

#define N 16384
#define D 256
#define C 1000
#define MARGIN 0.1f

#define WAVES 4
#define WR 32                    // rows per wave (one 32-row MFMA frag)
#define BM (WAVES * WR)          // 128 rows per block
#define BN 64                    // columns per tile step
#define COLSPLIT 8               // one column chunk per XCD
#define CCHUNK (N / COLSPLIT)    // 2048 columns per block
#define NT (CCHUNK / BN)         // 32 tiles
#define TILEB 32768              // bytes per 64-row tile in embT
#define LDSROW 528               // 512 + 16 pad (breaks pow2 stride)

typedef __attribute__((ext_vector_type(8))) short bf16x8;    // 4 VGPR
typedef __attribute__((ext_vector_type(16))) float f32x16;   // 32x32 C/D

// ---------------------------------------------------------------- prep ------
// One block per 64-row tile. Phase 1: each wave normalizes 16 rows (one row
// per iteration, coalesced float4 reads), stores bf16 rows into padded LDS.
// Phase 2: 16-B/lane coalesced writes in embT fragment order.
__global__ void __launch_bounds__(256) prep_kernel(
    const float* __restrict__ features,
    char* __restrict__ embT,
    unsigned* __restrict__ rowmax_enc) {
  __shared__ char sm[64 * LDSROW];  // 33.8 KB
  const int tid  = threadIdx.x;
  const int wave = tid >> 6;
  const int lane = tid & 63;
  const int tile = blockIdx.x;

#pragma unroll 4
  for (int rr = 0; rr < 16; ++rr) {
    const int r = wave * 16 + rr;          // row within tile
    const int row = tile * 64 + r;
    const float4 v =
        reinterpret_cast<const float4*>(features + (size_t)row * D)[lane];
    float ss = v.x * v.x + v.y * v.y + v.z * v.z + v.w * v.w;
#pragma unroll
    for (int off = 32; off >= 1; off >>= 1) ss += __shfl_xor(ss, off);
    const float inv = 1.0f / fmaxf(sqrtf(ss), 1e-12f);  // F.normalize eps

    __hip_bfloat16 e0 = __float2bfloat16(v.x * inv);
    __hip_bfloat16 e1 = __float2bfloat16(v.y * inv);
    __hip_bfloat16 e2 = __float2bfloat16(v.z * inv);
    __hip_bfloat16 e3 = __float2bfloat16(v.w * inv);
    ushort4 pack;
    pack.x = *reinterpret_cast<unsigned short*>(&e0);
    pack.y = *reinterpret_cast<unsigned short*>(&e1);
    pack.z = *reinterpret_cast<unsigned short*>(&e2);
    pack.w = *reinterpret_cast<unsigned short*>(&e3);
    // ds_write_b64, stride 8 B -> 2 lanes/bank (free).
    *reinterpret_cast<ushort4*>(sm + r * LDSROW + lane * 8) = pack;
  }
  __syncthreads();

  // Coalesced scatter into fragment order: dest byte d = is*4096 + tid*16.
#pragma unroll
  for (int is = 0; is < 8; ++is) {
    const int d   = is * 4096 + tid * 16;
    const int idx = d >> 10;               // ch*16 + kk, [0,32)
    const int c   = (d >> 4) & 31;
    const int kh  = (d >> 9) & 1;
    const int r   = (idx >> 4) * 32 + c;   // row within tile
    const int kbyte = (idx & 15) * 32 + kh * 16;
    const int4 val = *reinterpret_cast<const int4*>(sm + r * LDSROW + kbyte);
    *reinterpret_cast<int4*>(embT + (size_t)tile * TILEB + d) = val;
  }

  // ws re-poisoned (0xAA) before every timed launch -> re-init every call.
  // enc(-2.0f): bits 0xC0000000 (neg) -> enc = ~bits = 0x3FFFFFFF.
  if (tid < 64) rowmax_enc[tile * 64 + tid] = 0x3FFFFFFFu;
}

// -------------------------------------------------------------- pushmax -----
// 4 waves/block, wave owns 32 rows (A resident, 64 VGPR). C/D layout
// (HW-verified m74/m101): col = lane&31, row = (r&3)+8*(r>>2)+4*(lane>>5).
// A and B use the IDENTICAL (lane,reg)->(row,k) fragment map via embT, so
// any k-permutation cancels for E*E^T.
__global__ void __launch_bounds__(256, 3) pushmax_kernel(
    const char* __restrict__ embT,
    const int* __restrict__ target,
    unsigned* __restrict__ rowmax_enc) {
  const int tid  = threadIdx.x;
  const int wave = tid >> 6;
  const int lane = tid & 63;
  const int col  = lane & 31;
  const int kh   = lane >> 5;

  // XCD-aware: flat%8 == XCD (round-robin dispatch) == column chunk.
  // Per-XCD B working set = 2048 rows x 512 B = 1 MB -> L2-resident.
  const int flat = blockIdx.x;
  const int bx = flat >> 3;        // row panel    [0,128)
  const int by = flat & 7;         // column chunk [0,8)

  const int i0 = bx * BM + wave * WR;
  const int j0 = by * CCHUNK;

  // ---- A: 32 rows resident (64 VGPR). a[kk] = frag at (i0 tile, i0 ch).
  bf16x8 a[16];
  {
    const char* abase = embT + (size_t)(i0 >> 6) * TILEB +
                        ((i0 >> 5) & 1) * 16384 + lane * 16;
#pragma unroll
    for (int kk = 0; kk < 16; ++kk)
      a[kk] = *reinterpret_cast<const bf16x8*>(abase + kk * 1024);
  }

  // Row targets for the 16 C-regs, packed 2/int (C=1000 < 2^16).
  int tip[8];
#pragma unroll
  for (int p = 0; p < 8; ++p) {
    const int r0 = 2 * p, r1 = 2 * p + 1;
    const int row0 = (r0 & 3) + 8 * (r0 >> 2) + 4 * kh;
    const int row1 = (r1 & 3) + 8 * (r1 >> 2) + 4 * kh;
    tip[p] = (target[i0 + row0] & 0xffff) | (target[i0 + row1] << 16);
  }

  float rmax[16];
#pragma unroll
  for (int r = 0; r < 16; ++r) rmax[r] = -2.0f;

  for (int t = 0; t < NT; ++t) {
    const char* bbase = embT + (size_t)((j0 >> 6) + t) * TILEB + lane * 16;
    const int tjc[2] = {target[j0 + t * BN + col],
                        target[j0 + t * BN + 32 + col]};

#pragma unroll
    for (int ch = 0; ch < 2; ++ch) {
      f32x16 acc = {0.f, 0.f, 0.f, 0.f, 0.f, 0.f, 0.f, 0.f,
                    0.f, 0.f, 0.f, 0.f, 0.f, 0.f, 0.f, 0.f};
#pragma unroll
      for (int kk = 0; kk < 16; ++kk) {
        const bf16x8 b = *reinterpret_cast<const bf16x8*>(
            bbase + ch * 16384 + kk * 1024);
        acc = __builtin_amdgcn_mfma_f32_32x32x16_bf16(a[kk], b, acc, 0, 0, 0);
      }
      const int tj = tjc[ch];
#pragma unroll
      for (int r = 0; r < 16; ++r) {
        const int tiv = (tip[r >> 1] >> ((r & 1) << 4)) & 0xffff;
        rmax[r] = fmaxf(rmax[r], (tj != tiv) ? acc[r] : -2.0f);
      }
    }
  }

  // Reduce over the 32 columns each half-group holds (xor stays in-group).
#pragma unroll
  for (int off = 1; off < 32; off <<= 1)
#pragma unroll
    for (int r = 0; r < 16; ++r)
      rmax[r] = fmaxf(rmax[r], __shfl_xor(rmax[r], off));

  if (col == 0) {  // lanes 0 (kh=0) and 32 (kh=1)
#pragma unroll
    for (int r = 0; r < 16; ++r) {
      const unsigned bits = __float_as_uint(rmax[r]);
      const unsigned enc = bits ^ ((bits >> 31) ? 0xFFFFFFFFu : 0x80000000u);
      const int row = i0 + ((r & 3) + 8 * (r >> 2) + 4 * kh);
      atomicMax(&rowmax_enc[row], enc);  // device scope
    }
  }
}

// ------------------------------------------------------------- finalize -----
__global__ void __launch_bounds__(256) finalize_kernel(
    const unsigned* __restrict__ rowmax_enc,
    const float* __restrict__ cos_theta,
    const int* __restrict__ target,
    float* __restrict__ out) {
  const int i = blockIdx.x * 256 + (int)threadIdx.x;
  const unsigned enc = rowmax_enc[i];
  const unsigned bits = (enc & 0x80000000u) ? (enc ^ 0x80000000u) : ~enc;
  const float m = __uint_as_float(bits);
  const int t = target[i];
  const float thr = fmaxf(cos_theta[(size_t)i * C + t], MARGIN) - MARGIN;
  float local = fmaxf(m - thr, 0.0f) * (1.0f / (float)N);

#pragma unroll
  for (int off = 32; off >= 1; off >>= 1) local += __shfl_xor(local, off);

  __shared__ float ss[4];
  const int wid = threadIdx.x >> 6;
  if ((threadIdx.x & 63) == 0) ss[wid] = local;
  __syncthreads();
  if (threadIdx.x == 0) atomicAdd(out, ss[0] + ss[1] + ss[2] + ss[3]);
}

// --------------------------------------------------------------- launch -----
extern "C" void kernel_launch(void* const* d_in, const int* in_sizes, int n_in,
                              void* d_out, int out_size, void* d_ws, size_t ws_size,
                              hipStream_t stream) {
  const float* features  = (const float*)d_in[0];
  const float* cos_theta = (const float*)d_in[1];
  const int*   target    = (const int*)d_in[2];
  float* out = (float*)d_out;

  char* embT = (char*)d_ws;                                   // 8 MB
  unsigned* rowmax_enc = (unsigned*)((char*)d_ws + (size_t)(N / 64) * TILEB);

  prep_kernel<<<N / 64, 256, 0, stream>>>(features, embT, rowmax_enc);

  pushmax_kernel<<<(N / BM) * COLSPLIT, 256, 0, stream>>>(embT, target,
                                                          rowmax_enc);

  hipMemsetAsync(out, 0, sizeof(float), stream);
  finalize_kernel<<<N / 256, 256, 0, stream>>>(rowmax_enc, cos_theta, target,
                                               out);
}

// Round 12
// 271.194 us; speedup vs baseline: 1.7809x; 1.7809x over previous
//
#include <hip/hip_runtime.h>
#include <hip/hip_bf16.h>

// LocalPushLoss on MI355X (gfx950).
// losses[i] = max(0, M_i - thr_i),
//   M_i  = max over j with target[j]!=target[i] of <emb_i, emb_j>
//   thr_i = max(cos_theta[i, target[i]], 0.1) - 0.1
// out = mean(losses). bf16 MFMA GEMM E*E^T (N=16384, D=256) + fused masked
// row-max. 137.4 GFLOP -> 54.6us floor.
//
// Round-7 theory (from r4/r6 counters): compiler refuses to keep the A
// fragment array resident (r6: VGPR_Count=76 -> a[] loads sunk into loop,
// ~2 global loads/MFMA, latency-bound, MfmaUtil 14.6%). Direct-L2 B also
// exceeds the 56 B/cyc/CU L2 ceiling at 1 MFMA/KB. Fixes:
//  - WR=64, a[2][16] PINNED via asm volatile "+v" (no remat possible);
//    2 MFMA per B fragment.
//  - B staged via LDS double buffer (linear global_load_lds w16; embT is
//    already fragment-ordered), conflict-free ds_read_b128.
//  - 512 blocks = 2/CU resident, __launch_bounds__(256,2).
// embT layout (verified absmax=0.0 in r4/r6 benches):
//   byte(tile,ch,kk,kh,c,half) = tile*32768 + ch*16384 + kk*1024
//                              + (kh*32+c)*16 + half*8
//   row = tile*64 + ch*32 + c ; k = kk*16 + kh*8 + half*4 ..+4

#define N 16384
#define D 256
#define C 1000
#define MARGIN 0.1f

#define WAVES 4
#define WR 64                    // rows per wave (2 x 32-row MFMA frags)
#define BM (WAVES * WR)          // 256 rows per block
#define BN 64                    // columns per LDS tile
#define COLSPLIT 8               // one column chunk per XCD
#define CCHUNK (N / COLSPLIT)    // 2048 columns per block
#define NT (CCHUNK / BN)         // 32 tiles
#define TILEB 32768              // bytes per 64-row tile in embT
#define LDSROW 528               // prep staging: 512 + 16 pad

typedef __attribute__((ext_vector_type(8))) short bf16x8;    // 4 VGPR
typedef __attribute__((ext_vector_type(16))) float f32x16;   // 32x32 C/D

// ---------------------------------------------------------------- prep ------
// One block per 64-row tile. Phase 1: waves normalize rows into padded LDS.
// Phase 2: 16-B/lane coalesced writes in embT fragment order.
__global__ void __launch_bounds__(256) prep_kernel(
    const float* __restrict__ features,
    char* __restrict__ embT,
    unsigned* __restrict__ rowmax_enc) {
  __shared__ char sm[64 * LDSROW];  // 33.8 KB
  const int tid  = threadIdx.x;
  const int wave = tid >> 6;
  const int lane = tid & 63;
  const int tile = blockIdx.x;

#pragma unroll 4
  for (int rr = 0; rr < 16; ++rr) {
    const int r = wave * 16 + rr;          // row within tile
    const int row = tile * 64 + r;
    const float4 v =
        reinterpret_cast<const float4*>(features + (size_t)row * D)[lane];
    float ss = v.x * v.x + v.y * v.y + v.z * v.z + v.w * v.w;
#pragma unroll
    for (int off = 32; off >= 1; off >>= 1) ss += __shfl_xor(ss, off);
    const float inv = 1.0f / fmaxf(sqrtf(ss), 1e-12f);  // F.normalize eps

    __hip_bfloat16 e0 = __float2bfloat16(v.x * inv);
    __hip_bfloat16 e1 = __float2bfloat16(v.y * inv);
    __hip_bfloat16 e2 = __float2bfloat16(v.z * inv);
    __hip_bfloat16 e3 = __float2bfloat16(v.w * inv);
    ushort4 pack;
    pack.x = *reinterpret_cast<unsigned short*>(&e0);
    pack.y = *reinterpret_cast<unsigned short*>(&e1);
    pack.z = *reinterpret_cast<unsigned short*>(&e2);
    pack.w = *reinterpret_cast<unsigned short*>(&e3);
    *reinterpret_cast<ushort4*>(sm + r * LDSROW + lane * 8) = pack;
  }
  __syncthreads();

  // Coalesced scatter into fragment order: dest byte d = is*4096 + tid*16.
#pragma unroll
  for (int is = 0; is < 8; ++is) {
    const int d   = is * 4096 + tid * 16;
    const int idx = d >> 10;               // ch*16 + kk, [0,32)
    const int c   = (d >> 4) & 31;
    const int kh  = (d >> 9) & 1;
    const int r   = (idx >> 4) * 32 + c;   // row within tile
    const int kbyte = (idx & 15) * 32 + kh * 16;
    const int4 val = *reinterpret_cast<const int4*>(sm + r * LDSROW + kbyte);
    *reinterpret_cast<int4*>(embT + (size_t)tile * TILEB + d) = val;
  }

  // ws re-poisoned (0xAA) before every timed launch -> re-init every call.
  // enc(-2.0f): bits 0xC0000000 (neg) -> enc = ~bits = 0x3FFFFFFF.
  if (tid < 64) rowmax_enc[tile * 64 + tid] = 0x3FFFFFFFu;
}

// -------------------------------------------------------------- pushmax -----
// 4 waves/block, wave owns 64 rows (one embT tile; A pinned in 128 VGPR).
// C/D layout (HW-verified m74/m101): col = lane&31,
// row = (r&3)+8*(r>>2)+4*(lane>>5).
// A and B use the IDENTICAL (lane,reg)->(row,k) fragment map via embT, so
// any k-permutation cancels for E*E^T.
__global__ void __launch_bounds__(256, 2) pushmax_kernel(
    const char* __restrict__ embT,
    const int* __restrict__ target,
    unsigned* __restrict__ rowmax_enc) {
  __shared__ char lds[2 * TILEB];  // 64 KB double buffer -> 2 blocks/CU

  const int tid  = threadIdx.x;
  const int wave = tid >> 6;
  const int lane = tid & 63;
  const int col  = lane & 31;
  const int kh   = lane >> 5;

  // XCD-aware: flat%8 == XCD (round-robin dispatch) == column chunk.
  // Per-XCD B working set = 2048 rows x 512 B = 1 MB -> L2-resident.
  const int flat = blockIdx.x;
  const int bx = flat >> 3;        // row panel    [0,64)
  const int by = flat & 7;         // column chunk [0,8)

  const int i0 = bx * BM + wave * WR;   // 64-aligned
  const int j0 = by * CCHUNK;

  // ---- stage: linear copy, embT tile already in fragment order.
  // LDS dest = wave-uniform base + lane*16 (HW scatter contract).
  auto STAGE = [&](int buf, int t) {
#pragma unroll
    for (int is = 0; is < 8; ++is) {
      const char* g = embT + (size_t)((j0 >> 6) + t) * TILEB + is * 4096 +
                      tid * 16;
      char* l = lds + buf * TILEB + is * 4096 + tid * 16;
      __builtin_amdgcn_global_load_lds(
          (const __attribute__((address_space(1))) unsigned int*)g,
          (__attribute__((address_space(3))) unsigned int*)l, 16, 0, 0);
    }
  };

  STAGE(0, 0);  // prologue stage overlaps A/target loads below

  // ---- A: 64 rows resident. a[f][kk] = embT[i0>>6][f][kk][lane].
  bf16x8 a[2][16];
  {
    const char* abase = embT + (size_t)(i0 >> 6) * TILEB + lane * 16;
#pragma unroll
    for (int f = 0; f < 2; ++f)
#pragma unroll
      for (int kk = 0; kk < 16; ++kk)
        a[f][kk] =
            *reinterpret_cast<const bf16x8*>(abase + f * 16384 + kk * 1024);
  }
  // Pin: opaque touch defeats load-sinking/remat (r6: VGPR=76 showed the
  // compiler otherwise re-issues these global loads inside the K-loop).
#pragma unroll
  for (int f = 0; f < 2; ++f)
#pragma unroll
    for (int kk = 0; kk < 16; ++kk)
      asm volatile("" : "+v"(a[f][kk]));

  // Row targets for the 16 C-regs per frag, packed 2/int (C=1000 < 2^16).
  int tip[2][8];
#pragma unroll
  for (int f = 0; f < 2; ++f)
#pragma unroll
    for (int p = 0; p < 8; ++p) {
      const int r0 = 2 * p, r1 = 2 * p + 1;
      const int row0 = (r0 & 3) + 8 * (r0 >> 2) + 4 * kh;
      const int row1 = (r1 & 3) + 8 * (r1 >> 2) + 4 * kh;
      tip[f][p] = (target[i0 + f * 32 + row0] & 0xffff) |
                  (target[i0 + f * 32 + row1] << 16);
    }

  float rmax[2][16];
#pragma unroll
  for (int f = 0; f < 2; ++f)
#pragma unroll
    for (int r = 0; r < 16; ++r) rmax[f][r] = -2.0f;

  __syncthreads();  // prologue stage drained (vmcnt0 before barrier)

  for (int t = 0; t < NT; ++t) {
    const int cur = t & 1;
    if (t + 1 < NT) STAGE(cur ^ 1, t + 1);  // in flight across this compute

    const int tj0 = target[j0 + t * BN + col];
    const int tj1 = target[j0 + t * BN + 32 + col];

    const char* base = lds + cur * TILEB + lane * 16;
#pragma unroll
    for (int ch = 0; ch < 2; ++ch) {
      f32x16 acc0 = {0.f, 0.f, 0.f, 0.f, 0.f, 0.f, 0.f, 0.f,
                     0.f, 0.f, 0.f, 0.f, 0.f, 0.f, 0.f, 0.f};
      f32x16 acc1 = acc0;
#pragma unroll
      for (int kk = 0; kk < 16; ++kk) {
        const bf16x8 b = *reinterpret_cast<const bf16x8*>(
            base + ch * 16384 + kk * 1024);               // ds_read_b128
        acc0 = __builtin_amdgcn_mfma_f32_32x32x16_bf16(a[0][kk], b, acc0, 0, 0, 0);
        acc1 = __builtin_amdgcn_mfma_f32_32x32x16_bf16(a[1][kk], b, acc1, 0, 0, 0);
      }
      const int tj = ch ? tj1 : tj0;
#pragma unroll
      for (int r = 0; r < 16; ++r) {
        const int tiv0 = (tip[0][r >> 1] >> ((r & 1) << 4)) & 0xffff;
        const int tiv1 = (tip[1][r >> 1] >> ((r & 1) << 4)) & 0xffff;
        rmax[0][r] = fmaxf(rmax[0][r], (tj != tiv0) ? acc0[r] : -2.0f);
        rmax[1][r] = fmaxf(rmax[1][r], (tj != tiv1) ? acc1[r] : -2.0f);
      }
    }
    __syncthreads();  // stage(t+1) drained; all readers done with cur
  }

  // Reduce over the 32 columns each half-group holds (xor stays in-group).
#pragma unroll
  for (int off = 1; off < 32; off <<= 1)
#pragma unroll
    for (int f = 0; f < 2; ++f)
#pragma unroll
      for (int r = 0; r < 16; ++r)
        rmax[f][r] = fmaxf(rmax[f][r], __shfl_xor(rmax[f][r], off));

  if (col == 0) {  // lanes 0 (kh=0) and 32 (kh=1)
#pragma unroll
    for (int f = 0; f < 2; ++f)
#pragma unroll
      for (int r = 0; r < 16; ++r) {
        const unsigned bits = __float_as_uint(rmax[f][r]);
        const unsigned enc = bits ^ ((bits >> 31) ? 0xFFFFFFFFu : 0x80000000u);
        const int row = i0 + f * 32 + ((r & 3) + 8 * (r >> 2) + 4 * kh);
        atomicMax(&rowmax_enc[row], enc);  // device scope
      }
  }
}

// ------------------------------------------------------------- finalize -----
__global__ void __launch_bounds__(256) finalize_kernel(
    const unsigned* __restrict__ rowmax_enc,
    const float* __restrict__ cos_theta,
    const int* __restrict__ target,
    float* __restrict__ out) {
  const int i = blockIdx.x * 256 + (int)threadIdx.x;
  const unsigned enc = rowmax_enc[i];
  const unsigned bits = (enc & 0x80000000u) ? (enc ^ 0x80000000u) : ~enc;
  const float m = __uint_as_float(bits);
  const int t = target[i];
  const float thr = fmaxf(cos_theta[(size_t)i * C + t], MARGIN) - MARGIN;
  float local = fmaxf(m - thr, 0.0f) * (1.0f / (float)N);

#pragma unroll
  for (int off = 32; off >= 1; off >>= 1) local += __shfl_xor(local, off);

  __shared__ float ss[4];
  const int wid = threadIdx.x >> 6;
  if ((threadIdx.x & 63) == 0) ss[wid] = local;
  __syncthreads();
  if (threadIdx.x == 0) atomicAdd(out, ss[0] + ss[1] + ss[2] + ss[3]);
}

// --------------------------------------------------------------- launch -----
extern "C" void kernel_launch(void* const* d_in, const int* in_sizes, int n_in,
                              void* d_out, int out_size, void* d_ws, size_t ws_size,
                              hipStream_t stream) {
  const float* features  = (const float*)d_in[0];
  const float* cos_theta = (const float*)d_in[1];
  const int*   target    = (const int*)d_in[2];
  float* out = (float*)d_out;

  char* embT = (char*)d_ws;                                   // 8 MB
  unsigned* rowmax_enc = (unsigned*)((char*)d_ws + (size_t)(N / 64) * TILEB);

  prep_kernel<<<N / 64, 256, 0, stream>>>(features, embT, rowmax_enc);

  pushmax_kernel<<<(N / BM) * COLSPLIT, 256, 0, stream>>>(embT, target,
                                                          rowmax_enc);

  hipMemsetAsync(out, 0, sizeof(float), stream);
  finalize_kernel<<<N / 256, 256, 0, stream>>>(rowmax_enc, cos_theta, target,
                                               out);
}